// Round 3
// baseline (377.234 us; speedup 1.0000x reference)
//
#include <hip/hip_runtime.h>
#include <hip/hip_bf16.h>

// ---------------- problem constants ----------------
#define NSEQ 2048
#define HIDDIM 1024
#define NH 16
#define DHEAD 64
#define NW 129      // 2*WK+1
#define AKS 132     // padded a_k row stride (floats)

typedef float          f32x4 __attribute__((ext_vector_type(4)));
typedef _Float16       f16x4 __attribute__((ext_vector_type(4)));
typedef _Float16       f16x8 __attribute__((ext_vector_type(8)));
typedef unsigned short u16x8 __attribute__((ext_vector_type(8)));
typedef unsigned short u16;

__device__ __forceinline__ float b2f(u16 u){ return __uint_as_float(((unsigned)u) << 16); }
// dtype-hedged scalar load: flag=1 -> bf16, flag=0 -> f32
__device__ __forceinline__ float ld_any(const void* p, long idx, int flag){
  return flag ? b2f(((const u16*)p)[idx]) : ((const float*)p)[idx];
}

// ---------------- workspace layout (all 16B aligned) ----------------
static const size_t OFF_Q    = 0;                        // f16 [H][N][DH]      4 MiB
static const size_t OFF_K    = (size_t)4  << 20;         // f16 [H][N][DH]      4 MiB
static const size_t OFF_VT   = (size_t)8  << 20;         // f16 [H][DH][N]      4 MiB
static const size_t OFF_WT   = (size_t)12 << 20;         // f16 [3][1024][1024] 6 MiB (transposed [o][k])
static const size_t OFF_AK   = (size_t)18 << 20;         // f32 [H][N][AKS]     16.5 MiB
static const size_t OFF_M    = OFF_AK + (size_t)NH * NSEQ * AKS * 4;
static const size_t OFF_L    = OFF_M + (size_t)NH * NSEQ * 4;
static const size_t OFF_CTX  = OFF_L + (size_t)NH * NSEQ * 4;        // f32 [N][HID] 8 MiB
static const size_t OFF_HSF  = OFF_CTX + (size_t)NSEQ * HIDDIM * 4;  // f16 [N][HID] 4 MiB
static const size_t OFF_BIAS = OFF_HSF + (size_t)NSEQ * HIDDIM * 2;  // f32 [3][1024]
static const size_t OFF_WRK  = OFF_BIAS + 3 * 1024 * 4;              // f32 [64][129]
static const size_t OFF_WRV  = OFF_WRK + (size_t)DHEAD * NW * 4;     // f32 [129][64]
static const size_t OFF_EXT  = OFF_WRV + (size_t)NW * DHEAD * 4;     // f32 [N]
static const size_t OFF_FLAG = OFF_EXT + (size_t)NSEQ * 4;           // int

// ---------------- detect input dtype ----------------
// attention_mask is all-ones. As f32: word0 = 0x3F800000. As bf16 pair: 0x3F803F80.
__global__ void detect_kernel(const unsigned* __restrict__ mask_raw, int* __restrict__ flagp){
  *flagp = (mask_raw[0] == 0x3F800000u) ? 0 : 1;
}

// ---------------- convert hs -> f16 canonical ----------------
__global__ void cvt_hs_kernel(const void* __restrict__ hs, const int* __restrict__ flagp,
                              _Float16* __restrict__ hsf){
  const int flag = *flagp;
  const long base = (long)(blockIdx.x * 256 + threadIdx.x) * 8;
  f16x8 o;
  if (flag){
    const u16* b = (const u16*)hs;
#pragma unroll
    for (int e = 0; e < 8; e++) o[e] = (_Float16)b2f(b[base + e]);
  } else {
    const float* f = (const float*)hs;
#pragma unroll
    for (int e = 0; e < 8; e++) o[e] = (_Float16)f[base + e];
  }
  *(f16x8*)(hsf + base) = o;
}

// ---------------- convert small tensors -> f32 canonical ----------------
__global__ void cvt_small_kernel(const void* __restrict__ bq, const void* __restrict__ bk,
                                 const void* __restrict__ bv, const void* __restrict__ wrk,
                                 const void* __restrict__ wrv, const void* __restrict__ mask,
                                 const int* __restrict__ flagp,
                                 float* __restrict__ biasf, float* __restrict__ wrkf,
                                 float* __restrict__ wrvf, float* __restrict__ extf){
  const int flag = *flagp;
  const int idx = blockIdx.x * 256 + threadIdx.x;
  if (idx < 1024)            biasf[idx] = ld_any(bq, idx, flag);
  else if (idx < 2048)       biasf[idx] = ld_any(bk, idx - 1024, flag);
  else if (idx < 3072)       biasf[idx] = ld_any(bv, idx - 2048, flag);
  else if (idx < 3072 + 8256)  wrkf[idx - 3072]  = ld_any(wrk, idx - 3072, flag);
  else if (idx < 3072 + 16512) wrvf[idx - 11328] = ld_any(wrv, idx - 11328, flag);
  else if (idx < 3072 + 16512 + 2048)
    extf[idx - 19584] = (1.f - ld_any(mask, idx - 19584, flag)) * -1.0e30f;
}

// ---------------- transpose Wq/Wk/Wv -> Wt[o][k] f16 ----------------
__global__ void wtrans_kernel(const void* __restrict__ Wq, const void* __restrict__ Wk,
                              const void* __restrict__ Wv, const int* __restrict__ flagp,
                              _Float16* __restrict__ Wt){
  __shared__ __attribute__((aligned(16))) _Float16 tile[64][65];
  const int flag = *flagp;
  const int z = blockIdx.z;
  const void* src = (z == 0) ? Wq : ((z == 1) ? Wk : Wv);
  _Float16* dst = Wt + (size_t)z * 1024 * 1024;
  const int o0 = blockIdx.x * 64, k0 = blockIdx.y * 64;
  const int t = threadIdx.x;
#pragma unroll
  for (int c = 0; c < 2; c++){
    int idx = t + 256 * c;
    int r = idx >> 3, c8 = (idx & 7) * 8;
    long off = (long)(k0 + r) * 1024 + o0 + c8;
#pragma unroll
    for (int e = 0; e < 8; e++) tile[r][c8 + e] = (_Float16)ld_any(src, off + e, flag);
  }
  __syncthreads();
#pragma unroll
  for (int c = 0; c < 2; c++){
    int idx = t + 256 * c;
    int orow = idx >> 3, k8 = (idx & 7) * 8;
    f16x8 v;
#pragma unroll
    for (int e = 0; e < 8; e++) v[e] = tile[k8 + e][orow];
    *(f16x8*)(dst + (size_t)(o0 + orow) * 1024 + k0 + k8) = v;
  }
}

// ---------------- QKV projection GEMM (f16 MFMA) ----------------
// C[n][o] = hsf[n][:] . W[:][o] + bias[o];  z selects q/k/v.
// q,k stored f16 [h][n][d]; v stored TRANSPOSED f16 [h][d][n].
__launch_bounds__(256, 2)
__global__ void qkv_kernel(const _Float16* __restrict__ hsf, const _Float16* __restrict__ Wt,
                           const float* __restrict__ biasf,
                           _Float16* __restrict__ Qf, _Float16* __restrict__ Kf,
                           _Float16* __restrict__ Vtf){
  __shared__ __attribute__((aligned(16))) _Float16 As[128 * 40];
  __shared__ __attribute__((aligned(16))) _Float16 Bs[128 * 40];
  const int z = blockIdx.z;
  const _Float16* Wz = Wt + (size_t)z * 1024 * 1024;
  const int o0 = blockIdx.x * 128, m0 = blockIdx.y * 128;
  const int t = threadIdx.x, lane = t & 63, wave = t >> 6;
  const int wm = wave >> 1, wn = wave & 1;
  const int q = lane >> 4, ln = lane & 15;
  f32x4 acc[4][4];
#pragma unroll
  for (int a = 0; a < 4; a++)
#pragma unroll
    for (int b = 0; b < 4; b++) acc[a][b] = (f32x4){0.f, 0.f, 0.f, 0.f};

  for (int k0 = 0; k0 < 1024; k0 += 32){
#pragma unroll
    for (int c = 0; c < 2; c++){
      int idx = t + 256 * c;
      int r = idx >> 2, col = (idx & 3) * 8;
      *(f16x8*)&As[r * 40 + col] = *(const f16x8*)(hsf + (size_t)(m0 + r) * 1024 + k0 + col);
      *(f16x8*)&Bs[r * 40 + col] = *(const f16x8*)(Wz + (size_t)(o0 + r) * 1024 + k0 + col);
    }
    __syncthreads();
    f16x8 af[4], bf[4];
#pragma unroll
    for (int mt = 0; mt < 4; mt++) af[mt] = *(const f16x8*)&As[(wm * 64 + mt * 16 + ln) * 40 + q * 8];
#pragma unroll
    for (int nt = 0; nt < 4; nt++) bf[nt] = *(const f16x8*)&Bs[(wn * 64 + nt * 16 + ln) * 40 + q * 8];
#pragma unroll
    for (int mt = 0; mt < 4; mt++)
#pragma unroll
      for (int nt = 0; nt < 4; nt++)
        acc[mt][nt] = __builtin_amdgcn_mfma_f32_16x16x32_f16(af[mt], bf[nt], acc[mt][nt], 0, 0, 0);
    __syncthreads();
  }
  // epilogue: C layout col(lane&15)=o-dim, row(quad*4+reg)=n-dim
#pragma unroll
  for (int nt = 0; nt < 4; nt++){
    int o = o0 + wn * 64 + nt * 16 + ln;
    float bval = biasf[z * 1024 + o];
    int hh = o >> 6, dd = o & 63;
#pragma unroll
    for (int mt = 0; mt < 4; mt++){
      int nb = m0 + wm * 64 + mt * 16 + q * 4;
      if (z == 2){
        f16x4 pk;
#pragma unroll
        for (int r = 0; r < 4; r++) pk[r] = (_Float16)(acc[mt][nt][r] + bval);
        *(f16x4*)(Vtf + (size_t)(hh * 64 + dd) * 2048 + nb) = pk;
      } else {
        _Float16* dstp = (z == 0) ? Qf : Kf;
#pragma unroll
        for (int r = 0; r < 4; r++)
          dstp[(size_t)(hh * 2048 + nb + r) * 64 + dd] = (_Float16)(acc[mt][nt][r] + bval);
      }
    }
  }
}

// ---------------- a_k[h][i][w] = Q[h][i][:] . W_rel_k[:][w] ----------------
__launch_bounds__(256, 2)
__global__ void ak_kernel(const _Float16* __restrict__ Qf, const float* __restrict__ wrkf,
                          float* __restrict__ ak){
  __shared__ __attribute__((aligned(16))) _Float16 WrkT[144 * 72]; // [w][d], zero-pad w>=129
  const int h = blockIdx.y;
  const int i0 = blockIdx.x * 128;
  const int t = threadIdx.x, lane = t & 63, wave = t >> 6;
  const int q = lane >> 4, ln = lane & 15;
  for (int c = 0; c < 36; c++){
    int idx = t + 256 * c;
    int w = idx >> 6, d = idx & 63;
    float v = (w < NW) ? wrkf[d * NW + w] : 0.f;
    WrkT[w * 72 + d] = (_Float16)v;
  }
  __syncthreads();
  f16x8 afr[2][2];
#pragma unroll
  for (int mt = 0; mt < 2; mt++){
    int row = i0 + wave * 32 + mt * 16 + ln;
#pragma unroll
    for (int ks = 0; ks < 2; ks++)
      afr[mt][ks] = *(const f16x8*)(Qf + (size_t)(h * 2048 + row) * 64 + ks * 32 + q * 8);
  }
  f32x4 acc[2][9];
#pragma unroll
  for (int a = 0; a < 2; a++)
#pragma unroll
    for (int b = 0; b < 9; b++) acc[a][b] = (f32x4){0.f, 0.f, 0.f, 0.f};
#pragma unroll
  for (int nt = 0; nt < 9; nt++){
    f16x8 bfr0 = *(const f16x8*)&WrkT[(nt * 16 + ln) * 72 + q * 8];
    f16x8 bfr1 = *(const f16x8*)&WrkT[(nt * 16 + ln) * 72 + 32 + q * 8];
#pragma unroll
    for (int mt = 0; mt < 2; mt++){
      acc[mt][nt] = __builtin_amdgcn_mfma_f32_16x16x32_f16(afr[mt][0], bfr0, acc[mt][nt], 0, 0, 0);
      acc[mt][nt] = __builtin_amdgcn_mfma_f32_16x16x32_f16(afr[mt][1], bfr1, acc[mt][nt], 0, 0, 0);
    }
  }
#pragma unroll
  for (int nt = 0; nt < 9; nt++){
    int w = nt * 16 + ln;
    if (w > 128) continue;
#pragma unroll
    for (int mt = 0; mt < 2; mt++){
      int ib = i0 + wave * 32 + mt * 16 + q * 4;
#pragma unroll
      for (int r = 0; r < 4; r++)
        ak[(size_t)(h * 2048 + ib + r) * AKS + w] = acc[mt][nt][r];
    }
  }
}

// ---------------- flash attention (S^T trick) ----------------
__launch_bounds__(256, 2)
__global__ void flash_kernel(const float* __restrict__ extf,
                             const _Float16* __restrict__ Qf, const _Float16* __restrict__ Kf,
                             const _Float16* __restrict__ Vtf, const float* __restrict__ ak,
                             float* __restrict__ ctxws, float* __restrict__ mws,
                             float* __restrict__ lws){
  __shared__ __attribute__((aligned(16))) _Float16 Ks[128 * 72];   // K tile [j][d]
  __shared__ __attribute__((aligned(16))) _Float16 Vts[64 * 136];  // Vt tile [d][j]
  __shared__ __attribute__((aligned(16))) float exts[128];
  const int h = blockIdx.x, qt = blockIdx.y;
  const int t = threadIdx.x, lane = t & 63, wave = t >> 6;
  const int q = lane >> 4, ln = lane & 15;
  const int ibase = qt * 64 + wave * 16;
  const int i = ibase + ln;                 // this lane's query row
  f16x8 qfrag[2];
  {
    const _Float16* qrow = Qf + (size_t)(h * 2048 + i) * 64;
    qfrag[0] = *(const f16x8*)(qrow + q * 8);
    qfrag[1] = *(const f16x8*)(qrow + 32 + q * 8);
  }
  f32x4 accc[4];
#pragma unroll
  for (int dt = 0; dt < 4; dt++) accc[dt] = (f32x4){0.f, 0.f, 0.f, 0.f};
  float m_i = -1.0e30f, l_i = 0.f;
  const float* akrow = ak + (size_t)(h * 2048 + i) * AKS;

  for (int j0 = 0; j0 < 2048; j0 += 128){
    // ---- stage K, Vt, ext ----
#pragma unroll
    for (int c = 0; c < 4; c++){
      int idx = t + 256 * c;
      {
        int row = idx >> 3, col = idx & 7;
        *(f16x8*)&Ks[row * 72 + col * 8] =
            *(const f16x8*)(Kf + (size_t)(h * 2048 + j0 + row) * 64 + col * 8);
      }
      {
        int row = idx >> 4, col = idx & 15;
        *(f16x8*)&Vts[row * 136 + col * 8] =
            *(const f16x8*)(Vtf + (size_t)(h * 64 + row) * 2048 + j0 + col * 8);
      }
    }
    if (t < 128) exts[t] = extf[j0 + t];
    __syncthreads();
    // ---- S^T = K . Q^T ----
    f32x4 s[8];
#pragma unroll
    for (int mt = 0; mt < 8; mt++){
      f16x8 kf0 = *(const f16x8*)&Ks[(mt * 16 + ln) * 72 + q * 8];
      f16x8 kf1 = *(const f16x8*)&Ks[(mt * 16 + ln) * 72 + 32 + q * 8];
      f32x4 zz = (f32x4){0.f, 0.f, 0.f, 0.f};
      zz = __builtin_amdgcn_mfma_f32_16x16x32_f16(kf0, qfrag[0], zz, 0, 0, 0);
      zz = __builtin_amdgcn_mfma_f32_16x16x32_f16(kf1, qfrag[1], zz, 0, 0, 0);
      s[mt] = zz;
    }
    // ---- banded key bias + scale + mask ----
    const bool band = (j0 <= ibase + 79) && (j0 + 127 >= ibase - 64);
#pragma unroll
    for (int mt = 0; mt < 8; mt++){
      f32x4 ev = *(const f32x4*)&exts[mt * 16 + q * 4];
#pragma unroll
      for (int r = 0; r < 4; r++){
        float x = s[mt][r];
        if (band){
          int w = j0 + mt * 16 + q * 4 + r - i + 64;
          if ((unsigned)w <= 128u) x += akrow[w];
        }
        s[mt][r] = x * 0.125f + ev[r];
      }
    }
    // ---- online softmax (row i lives in lane&15, replicated over quads) ----
    float tmax = -1.0e30f;
#pragma unroll
    for (int mt = 0; mt < 8; mt++)
#pragma unroll
      for (int r = 0; r < 4; r++) tmax = fmaxf(tmax, s[mt][r]);
    tmax = fmaxf(tmax, __shfl_xor(tmax, 16, 64));
    tmax = fmaxf(tmax, __shfl_xor(tmax, 32, 64));
    float mnew = fmaxf(m_i, tmax);
    float alpha = __expf(m_i - mnew);
    m_i = mnew;
    l_i *= alpha;
#pragma unroll
    for (int dt = 0; dt < 4; dt++)
#pragma unroll
      for (int r = 0; r < 4; r++) accc[dt][r] *= alpha;
    float tsum = 0.f;
    f16x4 pf[8];
#pragma unroll
    for (int mt = 0; mt < 8; mt++)
#pragma unroll
      for (int r = 0; r < 4; r++){
        float p = __expf(s[mt][r] - mnew);
        tsum += p;
        pf[mt][r] = (_Float16)p;
      }
    tsum += __shfl_xor(tsum, 16, 64);
    tsum += __shfl_xor(tsum, 32, 64);
    l_i += tsum;
    // ---- PV: ctx^T[d][i] += Vt . P^T  (P^T C-layout == B-operand layout for K=16) ----
#pragma unroll
    for (int dt = 0; dt < 4; dt++){
#pragma unroll
      for (int ks = 0; ks < 8; ks++){
        f16x4 vf = *(const f16x4*)&Vts[(dt * 16 + ln) * 136 + ks * 16 + q * 4];
        accc[dt] = __builtin_amdgcn_mfma_f32_16x16x16f16(vf, pf[ks], accc[dt], 0, 0, 0);
      }
    }
    __syncthreads();
  }
  // ---- epilogue ----
  float invl = 1.f / l_i;
#pragma unroll
  for (int dt = 0; dt < 4; dt++){
    f32x4 o4;
#pragma unroll
    for (int r = 0; r < 4; r++) o4[r] = accc[dt][r] * invl;
    *(f32x4*)(ctxws + (size_t)i * 1024 + h * 64 + dt * 16 + q * 4) = o4;
  }
  if (q == 0){
    mws[h * 2048 + i] = m_i;
    lws[h * 2048 + i] = l_i;
  }
}

// ---------------- value-side band correction + final f32 store ----------------
__launch_bounds__(256, 4)
__global__ void band_kernel(const float* __restrict__ extf,
                            const _Float16* __restrict__ Qf, const _Float16* __restrict__ Kf,
                            const float* __restrict__ ak, const float* __restrict__ mws,
                            const float* __restrict__ lws, const float* __restrict__ wrvf,
                            const float* __restrict__ ctxws, float* __restrict__ out){
  __shared__ __attribute__((aligned(16))) float pband[4][132];
  const int t = threadIdx.x, lane = t & 63, wave = t >> 6;
  const int h = blockIdx.y;
  const int i = blockIdx.x * 4 + wave;
  const float m_i = mws[h * 2048 + i];
  const float invl = 1.f / lws[h * 2048 + i];
  const int j1 = i - 64 + lane;        // w = lane
  const int j2 = i + 1 + lane;         // w = 65 + lane
  const int j1c = (j1 < 0) ? 0 : j1;
  const int j2c = (j2 > 2047) ? 2047 : j2;
  float a1 = 0.f, a2 = 0.f, a0 = 0.f;
  const _Float16* qp = Qf + (size_t)(h * 2048 + i) * 64;
  const _Float16* kbase = Kf + (size_t)h * 2048 * 64;
#pragma unroll
  for (int cc = 0; cc < 8; cc++){
    f16x8 qv  = *(const f16x8*)(qp + cc * 8);
    f16x8 k1  = *(const f16x8*)(kbase + (size_t)j1c * 64 + cc * 8);
    f16x8 k2  = *(const f16x8*)(kbase + (size_t)j2c * 64 + cc * 8);
    f16x8 k0v = *(const f16x8*)(kbase + (size_t)i * 64 + cc * 8);
#pragma unroll
    for (int e = 0; e < 8; e++){
      float qe = (float)qv[e];
      a1 += qe * (float)k1[e];
      a2 += qe * (float)k2[e];
      a0 += qe * (float)k0v[e];
    }
  }
  const float* akrow = ak + (size_t)(h * 2048 + i) * AKS;
  float s1 = (a1 + akrow[lane]) * 0.125f + extf[j1c];
  float s2 = (a2 + akrow[65 + lane]) * 0.125f + extf[j2c];
  float s0 = (a0 + akrow[64]) * 0.125f + extf[i];
  float p1 = (j1 >= 0)   ? __expf(s1 - m_i) * invl : 0.f;
  float p2 = (j2 < 2048) ? __expf(s2 - m_i) * invl : 0.f;
  float p0 = __expf(s0 - m_i) * invl;
  pband[wave][lane] = p1;
  pband[wave][65 + lane] = p2;
  if (lane == 0) pband[wave][64] = p0;
  __syncthreads();
  float corr = 0.f;
  const float* pb = pband[wave];
  for (int w = 0; w < 128; w += 4){
    corr += pb[w]     * wrvf[(w)     * 64 + lane];
    corr += pb[w + 1] * wrvf[(w + 1) * 64 + lane];
    corr += pb[w + 2] * wrvf[(w + 2) * 64 + lane];
    corr += pb[w + 3] * wrvf[(w + 3) * 64 + lane];
  }
  corr += pb[128] * wrvf[128 * 64 + lane];
  out[(size_t)i * 1024 + h * 64 + lane] = ctxws[(size_t)i * 1024 + h * 64 + lane] + corr;
}

// ---------------- launcher ----------------
extern "C" void kernel_launch(void* const* d_in, const int* in_sizes, int n_in,
                              void* d_out, int out_size, void* d_ws, size_t ws_size,
                              hipStream_t stream){
  const void* hs   = d_in[0];
  const void* mask = d_in[1];
  const void* Wq   = d_in[2];
  const void* bq   = d_in[3];
  const void* Wk   = d_in[4];
  const void* bk   = d_in[5];
  const void* Wv   = d_in[6];
  const void* bv   = d_in[7];
  const void* Wrk  = d_in[8];
  const void* Wrv  = d_in[9];
  float* out = (float*)d_out;

  char* ws = (char*)d_ws;
  _Float16* Qf    = (_Float16*)(ws + OFF_Q);
  _Float16* Kf    = (_Float16*)(ws + OFF_K);
  _Float16* Vtf   = (_Float16*)(ws + OFF_VT);
  _Float16* Wt    = (_Float16*)(ws + OFF_WT);
  float*    akp   = (float*)   (ws + OFF_AK);
  float*    mp    = (float*)   (ws + OFF_M);
  float*    lp    = (float*)   (ws + OFF_L);
  float*    ctxp  = (float*)   (ws + OFF_CTX);
  _Float16* hsf   = (_Float16*)(ws + OFF_HSF);
  float*    biasf = (float*)   (ws + OFF_BIAS);
  float*    wrkf  = (float*)   (ws + OFF_WRK);
  float*    wrvf  = (float*)   (ws + OFF_WRV);
  float*    extf  = (float*)   (ws + OFF_EXT);
  int*      flagp = (int*)     (ws + OFF_FLAG);

  detect_kernel   <<<dim3(1),          1,   0, stream>>>((const unsigned*)mask, flagp);
  cvt_hs_kernel   <<<dim3(1024),       256, 0, stream>>>(hs, flagp, hsf);
  cvt_small_kernel<<<dim3(85),         256, 0, stream>>>(bq, bk, bv, Wrk, Wrv, mask, flagp,
                                                         biasf, wrkf, wrvf, extf);
  wtrans_kernel   <<<dim3(16, 16, 3),  256, 0, stream>>>(Wq, Wk, Wv, flagp, Wt);
  qkv_kernel      <<<dim3(8, 16, 3),   256, 0, stream>>>(hsf, Wt, biasf, Qf, Kf, Vtf);
  ak_kernel       <<<dim3(16, 16),     256, 0, stream>>>(Qf, wrkf, akp);
  flash_kernel    <<<dim3(16, 32),     256, 0, stream>>>(extf, Qf, Kf, Vtf, akp, ctxp, mp, lp);
  band_kernel     <<<dim3(512, 16),    256, 0, stream>>>(extf, Qf, Kf, akp, mp, lp, wrvf, ctxp, out);
}

// Round 4
// 239.005 us; speedup vs baseline: 1.5784x; 1.5784x over previous
//
#include <hip/hip_runtime.h>
#include <hip/hip_bf16.h>

// ---------------- problem constants ----------------
#define NSEQ 2048
#define HIDDIM 1024
#define NH 16
#define DHEAD 64
#define NW 129      // 2*WK+1
#define AKS 132     // padded a_k row stride (floats)

typedef float          f32x4 __attribute__((ext_vector_type(4)));
typedef _Float16       f16x4 __attribute__((ext_vector_type(4)));
typedef _Float16       f16x8 __attribute__((ext_vector_type(8)));
typedef unsigned short u16x8 __attribute__((ext_vector_type(8)));
typedef unsigned short u16;

__device__ __forceinline__ float b2f(u16 u){ return __uint_as_float(((unsigned)u) << 16); }
// dtype-hedged scalar load: flag=1 -> bf16, flag=0 -> f32
__device__ __forceinline__ float ld_any(const void* p, long idx, int flag){
  return flag ? b2f(((const u16*)p)[idx]) : ((const float*)p)[idx];
}

// ---------------- workspace layout (all 16B aligned) ----------------
static const size_t OFF_Q    = 0;                        // f16 [H][N][DH]      4 MiB
static const size_t OFF_K    = (size_t)4  << 20;         // f16 [H][N][DH]      4 MiB
static const size_t OFF_VT   = (size_t)8  << 20;         // f16 [H][DH][N]      4 MiB
static const size_t OFF_WT   = (size_t)12 << 20;         // f16 [3][1024][1024] 6 MiB (transposed [o][k])
static const size_t OFF_AK   = (size_t)18 << 20;         // f32 [H][N][AKS]; ak bias, overwritten by flash w/ band logits
static const size_t OFF_M    = OFF_AK + (size_t)NH * NSEQ * AKS * 4;
static const size_t OFF_L    = OFF_M + (size_t)NH * NSEQ * 4;
static const size_t OFF_CTX  = OFF_L + (size_t)NH * NSEQ * 4;        // f32 [N][HID] 8 MiB
static const size_t OFF_HSF  = OFF_CTX + (size_t)NSEQ * HIDDIM * 4;  // f16 [N][HID] 4 MiB
static const size_t OFF_BIAS = OFF_HSF + (size_t)NSEQ * HIDDIM * 2;  // f32 [3][1024]
static const size_t OFF_WRK  = OFF_BIAS + 3 * 1024 * 4;              // f32 [64][129]
static const size_t OFF_WRV  = OFF_WRK + (size_t)DHEAD * NW * 4;     // f32 [129][64]
static const size_t OFF_EXT  = OFF_WRV + (size_t)NW * DHEAD * 4;     // f32 [N]
static const size_t OFF_FLAG = OFF_EXT + (size_t)NSEQ * 4;           // int

// ---------------- detect input dtype ----------------
// attention_mask is all-ones. As f32: word0 = 0x3F800000. As bf16 pair: 0x3F803F80.
__global__ void detect_kernel(const unsigned* __restrict__ mask_raw, int* __restrict__ flagp){
  *flagp = (mask_raw[0] == 0x3F800000u) ? 0 : 1;
}

// ---------------- convert hs -> f16 canonical ----------------
__global__ void cvt_hs_kernel(const void* __restrict__ hs, const int* __restrict__ flagp,
                              _Float16* __restrict__ hsf){
  const int flag = *flagp;
  const long base = (long)(blockIdx.x * 256 + threadIdx.x) * 8;
  f16x8 o;
  if (flag){
    const u16* b = (const u16*)hs;
#pragma unroll
    for (int e = 0; e < 8; e++) o[e] = (_Float16)b2f(b[base + e]);
  } else {
    const float* f = (const float*)hs;
#pragma unroll
    for (int e = 0; e < 8; e++) o[e] = (_Float16)f[base + e];
  }
  *(f16x8*)(hsf + base) = o;
}

// ---------------- convert small tensors -> f32 canonical ----------------
__global__ void cvt_small_kernel(const void* __restrict__ bq, const void* __restrict__ bk,
                                 const void* __restrict__ bv, const void* __restrict__ wrk,
                                 const void* __restrict__ wrv, const void* __restrict__ mask,
                                 const int* __restrict__ flagp,
                                 float* __restrict__ biasf, float* __restrict__ wrkf,
                                 float* __restrict__ wrvf, float* __restrict__ extf){
  const int flag = *flagp;
  const int idx = blockIdx.x * 256 + threadIdx.x;
  if (idx < 1024)            biasf[idx] = ld_any(bq, idx, flag);
  else if (idx < 2048)       biasf[idx] = ld_any(bk, idx - 1024, flag);
  else if (idx < 3072)       biasf[idx] = ld_any(bv, idx - 2048, flag);
  else if (idx < 3072 + 8256)  wrkf[idx - 3072]  = ld_any(wrk, idx - 3072, flag);
  else if (idx < 3072 + 16512) wrvf[idx - 11328] = ld_any(wrv, idx - 11328, flag);
  else if (idx < 3072 + 16512 + 2048)
    extf[idx - 19584] = (1.f - ld_any(mask, idx - 19584, flag)) * -1.0e30f;
}

// ---------------- transpose Wq/Wk/Wv -> Wt[o][k] f16 ----------------
__global__ void wtrans_kernel(const void* __restrict__ Wq, const void* __restrict__ Wk,
                              const void* __restrict__ Wv, const int* __restrict__ flagp,
                              _Float16* __restrict__ Wt){
  __shared__ __attribute__((aligned(16))) _Float16 tile[64][65];
  const int flag = *flagp;
  const int z = blockIdx.z;
  const void* src = (z == 0) ? Wq : ((z == 1) ? Wk : Wv);
  _Float16* dst = Wt + (size_t)z * 1024 * 1024;
  const int o0 = blockIdx.x * 64, k0 = blockIdx.y * 64;
  const int t = threadIdx.x;
#pragma unroll
  for (int c = 0; c < 2; c++){
    int idx = t + 256 * c;
    int r = idx >> 3, c8 = (idx & 7) * 8;
    long off = (long)(k0 + r) * 1024 + o0 + c8;
#pragma unroll
    for (int e = 0; e < 8; e++) tile[r][c8 + e] = (_Float16)ld_any(src, off + e, flag);
  }
  __syncthreads();
#pragma unroll
  for (int c = 0; c < 2; c++){
    int idx = t + 256 * c;
    int orow = idx >> 3, k8 = (idx & 7) * 8;
    f16x8 v;
#pragma unroll
    for (int e = 0; e < 8; e++) v[e] = tile[k8 + e][orow];
    *(f16x8*)(dst + (size_t)(o0 + orow) * 1024 + k0 + k8) = v;
  }
}

// ---------------- QKV projection GEMM (f16 MFMA) ----------------
// C[n][o] = hsf[n][:] . W[:][o] + bias[o];  z selects q/k/v.
// q,k stored f16 [h][n][d]; v stored TRANSPOSED f16 [h][d][n].
__launch_bounds__(256, 2)
__global__ void qkv_kernel(const _Float16* __restrict__ hsf, const _Float16* __restrict__ Wt,
                           const float* __restrict__ biasf,
                           _Float16* __restrict__ Qf, _Float16* __restrict__ Kf,
                           _Float16* __restrict__ Vtf){
  __shared__ __attribute__((aligned(16))) _Float16 As[128 * 40];
  __shared__ __attribute__((aligned(16))) _Float16 Bs[128 * 40];
  const int z = blockIdx.z;
  const _Float16* Wz = Wt + (size_t)z * 1024 * 1024;
  const int o0 = blockIdx.x * 128, m0 = blockIdx.y * 128;
  const int t = threadIdx.x, lane = t & 63, wave = t >> 6;
  const int wm = wave >> 1, wn = wave & 1;
  const int q = lane >> 4, ln = lane & 15;
  f32x4 acc[4][4];
#pragma unroll
  for (int a = 0; a < 4; a++)
#pragma unroll
    for (int b = 0; b < 4; b++) acc[a][b] = (f32x4){0.f, 0.f, 0.f, 0.f};

  for (int k0 = 0; k0 < 1024; k0 += 32){
#pragma unroll
    for (int c = 0; c < 2; c++){
      int idx = t + 256 * c;
      int r = idx >> 2, col = (idx & 3) * 8;
      *(f16x8*)&As[r * 40 + col] = *(const f16x8*)(hsf + (size_t)(m0 + r) * 1024 + k0 + col);
      *(f16x8*)&Bs[r * 40 + col] = *(const f16x8*)(Wz + (size_t)(o0 + r) * 1024 + k0 + col);
    }
    __syncthreads();
    f16x8 af[4], bf[4];
#pragma unroll
    for (int mt = 0; mt < 4; mt++) af[mt] = *(const f16x8*)&As[(wm * 64 + mt * 16 + ln) * 40 + q * 8];
#pragma unroll
    for (int nt = 0; nt < 4; nt++) bf[nt] = *(const f16x8*)&Bs[(wn * 64 + nt * 16 + ln) * 40 + q * 8];
#pragma unroll
    for (int mt = 0; mt < 4; mt++)
#pragma unroll
      for (int nt = 0; nt < 4; nt++)
        acc[mt][nt] = __builtin_amdgcn_mfma_f32_16x16x32_f16(af[mt], bf[nt], acc[mt][nt], 0, 0, 0);
    __syncthreads();
  }
  // epilogue: C layout col(lane&15)=o-dim, row(quad*4+reg)=n-dim
#pragma unroll
  for (int nt = 0; nt < 4; nt++){
    int o = o0 + wn * 64 + nt * 16 + ln;
    float bval = biasf[z * 1024 + o];
    int hh = o >> 6, dd = o & 63;
#pragma unroll
    for (int mt = 0; mt < 4; mt++){
      int nb = m0 + wm * 64 + mt * 16 + q * 4;
      if (z == 2){
        f16x4 pk;
#pragma unroll
        for (int r = 0; r < 4; r++) pk[r] = (_Float16)(acc[mt][nt][r] + bval);
        *(f16x4*)(Vtf + (size_t)(hh * 64 + dd) * 2048 + nb) = pk;
      } else {
        _Float16* dstp = (z == 0) ? Qf : Kf;
#pragma unroll
        for (int r = 0; r < 4; r++)
          dstp[(size_t)(hh * 2048 + nb + r) * 64 + dd] = (_Float16)(acc[mt][nt][r] + bval);
      }
    }
  }
}

// ---------------- a_k[h][i][w] = Q[h][i][:] . W_rel_k[:][w] ----------------
__launch_bounds__(256, 2)
__global__ void ak_kernel(const _Float16* __restrict__ Qf, const float* __restrict__ wrkf,
                          float* __restrict__ ak){
  __shared__ __attribute__((aligned(16))) _Float16 WrkT[144 * 72]; // [w][d], zero-pad w>=129
  const int h = blockIdx.y;
  const int i0 = blockIdx.x * 128;
  const int t = threadIdx.x, lane = t & 63, wave = t >> 6;
  const int q = lane >> 4, ln = lane & 15;
  for (int c = 0; c < 36; c++){
    int idx = t + 256 * c;
    int w = idx >> 6, d = idx & 63;
    float v = (w < NW) ? wrkf[d * NW + w] : 0.f;
    WrkT[w * 72 + d] = (_Float16)v;
  }
  __syncthreads();
  f16x8 afr[2][2];
#pragma unroll
  for (int mt = 0; mt < 2; mt++){
    int row = i0 + wave * 32 + mt * 16 + ln;
#pragma unroll
    for (int ks = 0; ks < 2; ks++)
      afr[mt][ks] = *(const f16x8*)(Qf + (size_t)(h * 2048 + row) * 64 + ks * 32 + q * 8);
  }
  f32x4 acc[2][9];
#pragma unroll
  for (int a = 0; a < 2; a++)
#pragma unroll
    for (int b = 0; b < 9; b++) acc[a][b] = (f32x4){0.f, 0.f, 0.f, 0.f};
#pragma unroll
  for (int nt = 0; nt < 9; nt++){
    f16x8 bfr0 = *(const f16x8*)&WrkT[(nt * 16 + ln) * 72 + q * 8];
    f16x8 bfr1 = *(const f16x8*)&WrkT[(nt * 16 + ln) * 72 + 32 + q * 8];
#pragma unroll
    for (int mt = 0; mt < 2; mt++){
      acc[mt][nt] = __builtin_amdgcn_mfma_f32_16x16x32_f16(afr[mt][0], bfr0, acc[mt][nt], 0, 0, 0);
      acc[mt][nt] = __builtin_amdgcn_mfma_f32_16x16x32_f16(afr[mt][1], bfr1, acc[mt][nt], 0, 0, 0);
    }
  }
#pragma unroll
  for (int nt = 0; nt < 9; nt++){
    int w = nt * 16 + ln;
    if (w > 128) continue;
#pragma unroll
    for (int mt = 0; mt < 2; mt++){
      int ib = i0 + wave * 32 + mt * 16 + q * 4;
#pragma unroll
      for (int r = 0; r < 4; r++)
        ak[(size_t)(h * 2048 + ib + r) * AKS + w] = acc[mt][nt][r];
    }
  }
}

// ---------------- flash attention (S^T trick) ----------------
// Also writes the FINAL in-band logits back into the ak buffer (in place),
// so band_kernel can reconstruct band probs without recomputing q.k.
__launch_bounds__(256, 2)
__global__ void flash_kernel(const float* __restrict__ extf,
                             const _Float16* __restrict__ Qf, const _Float16* __restrict__ Kf,
                             const _Float16* __restrict__ Vtf, float* akm,
                             float* __restrict__ ctxws, float* __restrict__ mws,
                             float* __restrict__ lws){
  __shared__ __attribute__((aligned(16))) _Float16 Ks[128 * 72];   // K tile [j][d]
  __shared__ __attribute__((aligned(16))) _Float16 Vts[64 * 136];  // Vt tile [d][j]
  __shared__ __attribute__((aligned(16))) float exts[128];
  const int h = blockIdx.x, qt = blockIdx.y;
  const int t = threadIdx.x, lane = t & 63, wave = t >> 6;
  const int q = lane >> 4, ln = lane & 15;
  const int ibase = qt * 64 + wave * 16;
  const int i = ibase + ln;                 // this lane's query row
  f16x8 qfrag[2];
  {
    const _Float16* qrow = Qf + (size_t)(h * 2048 + i) * 64;
    qfrag[0] = *(const f16x8*)(qrow + q * 8);
    qfrag[1] = *(const f16x8*)(qrow + 32 + q * 8);
  }
  f32x4 accc[4];
#pragma unroll
  for (int dt = 0; dt < 4; dt++) accc[dt] = (f32x4){0.f, 0.f, 0.f, 0.f};
  float m_i = -1.0e30f, l_i = 0.f;
  float* akrow = akm + (size_t)(h * 2048 + i) * AKS;

  for (int j0 = 0; j0 < 2048; j0 += 128){
    // ---- stage K, Vt, ext ----
#pragma unroll
    for (int c = 0; c < 4; c++){
      int idx = t + 256 * c;
      {
        int row = idx >> 3, col = idx & 7;
        *(f16x8*)&Ks[row * 72 + col * 8] =
            *(const f16x8*)(Kf + (size_t)(h * 2048 + j0 + row) * 64 + col * 8);
      }
      {
        int row = idx >> 4, col = idx & 15;
        *(f16x8*)&Vts[row * 136 + col * 8] =
            *(const f16x8*)(Vtf + (size_t)(h * 64 + row) * 2048 + j0 + col * 8);
      }
    }
    if (t < 128) exts[t] = extf[j0 + t];
    __syncthreads();
    // ---- S^T = K . Q^T ----
    f32x4 s[8];
#pragma unroll
    for (int mt = 0; mt < 8; mt++){
      f16x8 kf0 = *(const f16x8*)&Ks[(mt * 16 + ln) * 72 + q * 8];
      f16x8 kf1 = *(const f16x8*)&Ks[(mt * 16 + ln) * 72 + 32 + q * 8];
      f32x4 zz = (f32x4){0.f, 0.f, 0.f, 0.f};
      zz = __builtin_amdgcn_mfma_f32_16x16x32_f16(kf0, qfrag[0], zz, 0, 0, 0);
      zz = __builtin_amdgcn_mfma_f32_16x16x32_f16(kf1, qfrag[1], zz, 0, 0, 0);
      s[mt] = zz;
    }
    // ---- banded key bias + scale + mask; write back final band logits ----
    const bool band = (j0 <= ibase + 79) && (j0 + 127 >= ibase - 64);
#pragma unroll
    for (int mt = 0; mt < 8; mt++){
      f32x4 ev = *(const f32x4*)&exts[mt * 16 + q * 4];
#pragma unroll
      for (int r = 0; r < 4; r++){
        float x = s[mt][r];
        int w = j0 + mt * 16 + q * 4 + r - i + 64;
        if (band && (unsigned)w <= 128u){
          x = (x + akrow[w]) * 0.125f + ev[r];
          akrow[w] = x;                 // final logit for the band pass
        } else {
          x = x * 0.125f + ev[r];
        }
        s[mt][r] = x;
      }
    }
    // ---- online softmax (row i lives in lane&15, replicated over quads) ----
    float tmax = -1.0e30f;
#pragma unroll
    for (int mt = 0; mt < 8; mt++)
#pragma unroll
      for (int r = 0; r < 4; r++) tmax = fmaxf(tmax, s[mt][r]);
    tmax = fmaxf(tmax, __shfl_xor(tmax, 16, 64));
    tmax = fmaxf(tmax, __shfl_xor(tmax, 32, 64));
    float mnew = fmaxf(m_i, tmax);
    float alpha = __expf(m_i - mnew);
    m_i = mnew;
    l_i *= alpha;
#pragma unroll
    for (int dt = 0; dt < 4; dt++)
#pragma unroll
      for (int r = 0; r < 4; r++) accc[dt][r] *= alpha;
    float tsum = 0.f;
    f16x4 pf[8];
#pragma unroll
    for (int mt = 0; mt < 8; mt++)
#pragma unroll
      for (int r = 0; r < 4; r++){
        float p = __expf(s[mt][r] - mnew);
        tsum += p;
        pf[mt][r] = (_Float16)p;
      }
    tsum += __shfl_xor(tsum, 16, 64);
    tsum += __shfl_xor(tsum, 32, 64);
    l_i += tsum;
    // ---- PV: ctx^T[d][i] += Vt . P^T  (P^T C-layout == B-operand layout for K=16) ----
#pragma unroll
    for (int dt = 0; dt < 4; dt++){
#pragma unroll
      for (int ks = 0; ks < 8; ks++){
        f16x4 vf = *(const f16x4*)&Vts[(dt * 16 + ln) * 136 + ks * 16 + q * 4];
        accc[dt] = __builtin_amdgcn_mfma_f32_16x16x16f16(vf, pf[ks], accc[dt], 0, 0, 0);
      }
    }
    __syncthreads();
  }
  // ---- epilogue ----
  float invl = 1.f / l_i;
#pragma unroll
  for (int dt = 0; dt < 4; dt++){
    f32x4 o4;
#pragma unroll
    for (int r = 0; r < 4; r++) o4[r] = accc[dt][r] * invl;
    *(f32x4*)(ctxws + (size_t)i * 1024 + h * 64 + dt * 16 + q * 4) = o4;
  }
  if (q == 0){
    mws[h * 2048 + i] = m_i;
    lws[h * 2048 + i] = l_i;
  }
}

// ---------------- value-side band correction + final f32 store ----------------
// sband = ak buffer, now holding final band logits from flash_kernel.
__launch_bounds__(256, 4)
__global__ void band_kernel(const float* __restrict__ sband, const float* __restrict__ mws,
                            const float* __restrict__ lws, const float* __restrict__ wrvf,
                            const float* __restrict__ ctxws, float* __restrict__ out){
  __shared__ __attribute__((aligned(16))) float pband[4][132];
  const int t = threadIdx.x, lane = t & 63, wave = t >> 6;
  const int h = blockIdx.y;
  const int i = blockIdx.x * 4 + wave;
  const float m_i = mws[h * 2048 + i];
  const float invl = 1.f / lws[h * 2048 + i];
  const float* srow = sband + (size_t)(h * 2048 + i) * AKS;
  const int j1 = i - 64 + lane;        // w = lane
  const int j2 = i + 1 + lane;         // w = 65 + lane
  float s1 = srow[lane];
  float s2 = srow[65 + lane];
  float p1 = (j1 >= 0)   ? __expf(s1 - m_i) * invl : 0.f;
  float p2 = (j2 < 2048) ? __expf(s2 - m_i) * invl : 0.f;
  pband[wave][lane] = p1;
  pband[wave][65 + lane] = p2;
  if (lane == 0) pband[wave][64] = __expf(srow[64] - m_i) * invl;  // j=i always valid
  // pband row is written and read by the same wave only; compiler inserts lgkmcnt waits.
  float corr = 0.f;
  const float* pb = pband[wave];
#pragma unroll 4
  for (int w = 0; w < 128; w += 4){
    corr += pb[w]     * wrvf[(w)     * 64 + lane];
    corr += pb[w + 1] * wrvf[(w + 1) * 64 + lane];
    corr += pb[w + 2] * wrvf[(w + 2) * 64 + lane];
    corr += pb[w + 3] * wrvf[(w + 3) * 64 + lane];
  }
  corr += pb[128] * wrvf[128 * 64 + lane];
  out[(size_t)i * 1024 + h * 64 + lane] = ctxws[(size_t)i * 1024 + h * 64 + lane] + corr;
}

// ---------------- launcher ----------------
extern "C" void kernel_launch(void* const* d_in, const int* in_sizes, int n_in,
                              void* d_out, int out_size, void* d_ws, size_t ws_size,
                              hipStream_t stream){
  const void* hs   = d_in[0];
  const void* mask = d_in[1];
  const void* Wq   = d_in[2];
  const void* bq   = d_in[3];
  const void* Wk   = d_in[4];
  const void* bk   = d_in[5];
  const void* Wv   = d_in[6];
  const void* bv   = d_in[7];
  const void* Wrk  = d_in[8];
  const void* Wrv  = d_in[9];
  float* out = (float*)d_out;

  char* ws = (char*)d_ws;
  _Float16* Qf    = (_Float16*)(ws + OFF_Q);
  _Float16* Kf    = (_Float16*)(ws + OFF_K);
  _Float16* Vtf   = (_Float16*)(ws + OFF_VT);
  _Float16* Wt    = (_Float16*)(ws + OFF_WT);
  float*    akp   = (float*)   (ws + OFF_AK);
  float*    mp    = (float*)   (ws + OFF_M);
  float*    lp    = (float*)   (ws + OFF_L);
  float*    ctxp  = (float*)   (ws + OFF_CTX);
  _Float16* hsf   = (_Float16*)(ws + OFF_HSF);
  float*    biasf = (float*)   (ws + OFF_BIAS);
  float*    wrkf  = (float*)   (ws + OFF_WRK);
  float*    wrvf  = (float*)   (ws + OFF_WRV);
  float*    extf  = (float*)   (ws + OFF_EXT);
  int*      flagp = (int*)     (ws + OFF_FLAG);

  detect_kernel   <<<dim3(1),          1,   0, stream>>>((const unsigned*)mask, flagp);
  cvt_hs_kernel   <<<dim3(1024),       256, 0, stream>>>(hs, flagp, hsf);
  cvt_small_kernel<<<dim3(85),         256, 0, stream>>>(bq, bk, bv, Wrk, Wrv, mask, flagp,
                                                         biasf, wrkf, wrvf, extf);
  wtrans_kernel   <<<dim3(16, 16, 3),  256, 0, stream>>>(Wq, Wk, Wv, flagp, Wt);
  qkv_kernel      <<<dim3(8, 16, 3),   256, 0, stream>>>(hsf, Wt, biasf, Qf, Kf, Vtf);
  ak_kernel       <<<dim3(16, 16),     256, 0, stream>>>(Qf, wrkf, akp);
  flash_kernel    <<<dim3(16, 32),     256, 0, stream>>>(extf, Qf, Kf, Vtf, akp, ctxp, mp, lp);
  band_kernel     <<<dim3(512, 16),    256, 0, stream>>>(akp, mp, lp, wrvf, ctxp, out);
}

// Round 5
// 208.361 us; speedup vs baseline: 1.8105x; 1.1471x over previous
//
#include <hip/hip_runtime.h>
#include <hip/hip_bf16.h>

// ---------------- problem constants ----------------
#define NSEQ 2048
#define HIDDIM 1024
#define NH 16
#define DHEAD 64
#define NW 129      // 2*WK+1
#define AKS 132     // padded a_k row stride (floats)

typedef float          f32x4 __attribute__((ext_vector_type(4)));
typedef _Float16       f16x4 __attribute__((ext_vector_type(4)));
typedef _Float16       f16x8 __attribute__((ext_vector_type(8)));
typedef unsigned short u16x8 __attribute__((ext_vector_type(8)));
typedef unsigned short u16;

__device__ __forceinline__ float b2f(u16 u){ return __uint_as_float(((unsigned)u) << 16); }
// dtype-hedged scalar load: flag=1 -> bf16, flag=0 -> f32
__device__ __forceinline__ float ld_any(const void* p, long idx, int flag){
  return flag ? b2f(((const u16*)p)[idx]) : ((const float*)p)[idx];
}

// ---------------- workspace layout (all 16B aligned) ----------------
static const size_t OFF_Q    = 0;                        // f16 [H][N][DH]      4 MiB
static const size_t OFF_K    = (size_t)4  << 20;         // f16 [H][N][DH]      4 MiB
static const size_t OFF_VT   = (size_t)8  << 20;         // f16 [H][DH][N]      4 MiB
static const size_t OFF_WT   = (size_t)12 << 20;         // f16 [3][1024][1024] 6 MiB (transposed [o][k])
static const size_t OFF_AK   = (size_t)18 << 20;         // f32 [H][N][AKS]; ak bias -> band logits
static const size_t OFF_M    = OFF_AK + (size_t)NH * NSEQ * AKS * 4;   // f32 [2][H][N]
static const size_t OFF_L    = OFF_M + (size_t)2 * NH * NSEQ * 4;      // f32 [2][H][N]
static const size_t OFF_CTXP = OFF_L + (size_t)2 * NH * NSEQ * 4;      // f32 [2][N][HID] 16 MiB
static const size_t OFF_HSF  = OFF_CTXP + (size_t)2 * NSEQ * HIDDIM * 4; // f16 [N][HID] 4 MiB
static const size_t OFF_BIAS = OFF_HSF + (size_t)NSEQ * HIDDIM * 2;    // f32 [3][1024]
static const size_t OFF_WRK  = OFF_BIAS + 3 * 1024 * 4;                // f32 [64][129]
static const size_t OFF_WRV  = OFF_WRK + (size_t)DHEAD * NW * 4;       // f32 [129][64]
static const size_t OFF_EXT  = OFF_WRV + (size_t)NW * DHEAD * 4;       // f32 [N]
static const size_t OFF_FLAG = OFF_EXT + (size_t)NSEQ * 4;             // int

// ---------------- detect input dtype ----------------
__global__ void detect_kernel(const unsigned* __restrict__ mask_raw, int* __restrict__ flagp){
  *flagp = (mask_raw[0] == 0x3F800000u) ? 0 : 1;
}

// ---------------- convert hs -> f16 canonical ----------------
__global__ void cvt_hs_kernel(const void* __restrict__ hs, const int* __restrict__ flagp,
                              _Float16* __restrict__ hsf){
  const int flag = *flagp;
  const long base = (long)(blockIdx.x * 256 + threadIdx.x) * 8;
  f16x8 o;
  if (flag){
    const u16* b = (const u16*)hs;
#pragma unroll
    for (int e = 0; e < 8; e++) o[e] = (_Float16)b2f(b[base + e]);
  } else {
    const float* f = (const float*)hs;
#pragma unroll
    for (int e = 0; e < 8; e++) o[e] = (_Float16)f[base + e];
  }
  *(f16x8*)(hsf + base) = o;
}

// ---------------- convert small tensors -> f32 canonical ----------------
__global__ void cvt_small_kernel(const void* __restrict__ bq, const void* __restrict__ bk,
                                 const void* __restrict__ bv, const void* __restrict__ wrk,
                                 const void* __restrict__ wrv, const void* __restrict__ mask,
                                 const int* __restrict__ flagp,
                                 float* __restrict__ biasf, float* __restrict__ wrkf,
                                 float* __restrict__ wrvf, float* __restrict__ extf){
  const int flag = *flagp;
  const int idx = blockIdx.x * 256 + threadIdx.x;
  if (idx < 1024)            biasf[idx] = ld_any(bq, idx, flag);
  else if (idx < 2048)       biasf[idx] = ld_any(bk, idx - 1024, flag);
  else if (idx < 3072)       biasf[idx] = ld_any(bv, idx - 2048, flag);
  else if (idx < 3072 + 8256)  wrkf[idx - 3072]  = ld_any(wrk, idx - 3072, flag);
  else if (idx < 3072 + 16512) wrvf[idx - 11328] = ld_any(wrv, idx - 11328, flag);
  else if (idx < 3072 + 16512 + 2048)
    extf[idx - 19584] = (1.f - ld_any(mask, idx - 19584, flag)) * -1.0e30f;
}

// ---------------- transpose Wq/Wk/Wv -> Wt[o][k] f16 ----------------
__global__ void wtrans_kernel(const void* __restrict__ Wq, const void* __restrict__ Wk,
                              const void* __restrict__ Wv, const int* __restrict__ flagp,
                              _Float16* __restrict__ Wt){
  __shared__ __attribute__((aligned(16))) _Float16 tile[64][65];
  const int flag = *flagp;
  const int z = blockIdx.z;
  const void* src = (z == 0) ? Wq : ((z == 1) ? Wk : Wv);
  _Float16* dst = Wt + (size_t)z * 1024 * 1024;
  const int o0 = blockIdx.x * 64, k0 = blockIdx.y * 64;
  const int t = threadIdx.x;
#pragma unroll
  for (int c = 0; c < 2; c++){
    int idx = t + 256 * c;
    int r = idx >> 3, c8 = (idx & 7) * 8;
    long off = (long)(k0 + r) * 1024 + o0 + c8;
#pragma unroll
    for (int e = 0; e < 8; e++) tile[r][c8 + e] = (_Float16)ld_any(src, off + e, flag);
  }
  __syncthreads();
#pragma unroll
  for (int c = 0; c < 2; c++){
    int idx = t + 256 * c;
    int orow = idx >> 3, k8 = (idx & 7) * 8;
    f16x8 v;
#pragma unroll
    for (int e = 0; e < 8; e++) v[e] = tile[k8 + e][orow];
    *(f16x8*)(dst + (size_t)(o0 + orow) * 1024 + k0 + k8) = v;
  }
}

// ---------------- QKV projection GEMM (f16 MFMA) ----------------
__launch_bounds__(256, 2)
__global__ void qkv_kernel(const _Float16* __restrict__ hsf, const _Float16* __restrict__ Wt,
                           const float* __restrict__ biasf,
                           _Float16* __restrict__ Qf, _Float16* __restrict__ Kf,
                           _Float16* __restrict__ Vtf){
  __shared__ __attribute__((aligned(16))) _Float16 As[128 * 40];
  __shared__ __attribute__((aligned(16))) _Float16 Bs[128 * 40];
  const int z = blockIdx.z;
  const _Float16* Wz = Wt + (size_t)z * 1024 * 1024;
  const int o0 = blockIdx.x * 128, m0 = blockIdx.y * 128;
  const int t = threadIdx.x, lane = t & 63, wave = t >> 6;
  const int wm = wave >> 1, wn = wave & 1;
  const int q = lane >> 4, ln = lane & 15;
  f32x4 acc[4][4];
#pragma unroll
  for (int a = 0; a < 4; a++)
#pragma unroll
    for (int b = 0; b < 4; b++) acc[a][b] = (f32x4){0.f, 0.f, 0.f, 0.f};

  for (int k0 = 0; k0 < 1024; k0 += 32){
#pragma unroll
    for (int c = 0; c < 2; c++){
      int idx = t + 256 * c;
      int r = idx >> 2, col = (idx & 3) * 8;
      *(f16x8*)&As[r * 40 + col] = *(const f16x8*)(hsf + (size_t)(m0 + r) * 1024 + k0 + col);
      *(f16x8*)&Bs[r * 40 + col] = *(const f16x8*)(Wz + (size_t)(o0 + r) * 1024 + k0 + col);
    }
    __syncthreads();
    f16x8 af[4], bf[4];
#pragma unroll
    for (int mt = 0; mt < 4; mt++) af[mt] = *(const f16x8*)&As[(wm * 64 + mt * 16 + ln) * 40 + q * 8];
#pragma unroll
    for (int nt = 0; nt < 4; nt++) bf[nt] = *(const f16x8*)&Bs[(wn * 64 + nt * 16 + ln) * 40 + q * 8];
#pragma unroll
    for (int mt = 0; mt < 4; mt++)
#pragma unroll
      for (int nt = 0; nt < 4; nt++)
        acc[mt][nt] = __builtin_amdgcn_mfma_f32_16x16x32_f16(af[mt], bf[nt], acc[mt][nt], 0, 0, 0);
    __syncthreads();
  }
#pragma unroll
  for (int nt = 0; nt < 4; nt++){
    int o = o0 + wn * 64 + nt * 16 + ln;
    float bval = biasf[z * 1024 + o];
    int hh = o >> 6, dd = o & 63;
#pragma unroll
    for (int mt = 0; mt < 4; mt++){
      int nb = m0 + wm * 64 + mt * 16 + q * 4;
      if (z == 2){
        f16x4 pk;
#pragma unroll
        for (int r = 0; r < 4; r++) pk[r] = (_Float16)(acc[mt][nt][r] + bval);
        *(f16x4*)(Vtf + (size_t)(hh * 64 + dd) * 2048 + nb) = pk;
      } else {
        _Float16* dstp = (z == 0) ? Qf : Kf;
#pragma unroll
        for (int r = 0; r < 4; r++)
          dstp[(size_t)(hh * 2048 + nb + r) * 64 + dd] = (_Float16)(acc[mt][nt][r] + bval);
      }
    }
  }
}

// ---------------- a_k[h][i][w] = Q[h][i][:] . W_rel_k[:][w] ----------------
__launch_bounds__(256, 2)
__global__ void ak_kernel(const _Float16* __restrict__ Qf, const float* __restrict__ wrkf,
                          float* __restrict__ ak){
  __shared__ __attribute__((aligned(16))) _Float16 WrkT[144 * 72]; // [w][d], zero-pad w>=129
  const int h = blockIdx.y;
  const int i0 = blockIdx.x * 128;
  const int t = threadIdx.x, lane = t & 63, wave = t >> 6;
  const int q = lane >> 4, ln = lane & 15;
  for (int c = 0; c < 36; c++){
    int idx = t + 256 * c;
    int w = idx >> 6, d = idx & 63;
    float v = (w < NW) ? wrkf[d * NW + w] : 0.f;
    WrkT[w * 72 + d] = (_Float16)v;
  }
  __syncthreads();
  f16x8 afr[2][2];
#pragma unroll
  for (int mt = 0; mt < 2; mt++){
    int row = i0 + wave * 32 + mt * 16 + ln;
#pragma unroll
    for (int ks = 0; ks < 2; ks++)
      afr[mt][ks] = *(const f16x8*)(Qf + (size_t)(h * 2048 + row) * 64 + ks * 32 + q * 8);
  }
  f32x4 acc[2][9];
#pragma unroll
  for (int a = 0; a < 2; a++)
#pragma unroll
    for (int b = 0; b < 9; b++) acc[a][b] = (f32x4){0.f, 0.f, 0.f, 0.f};
#pragma unroll
  for (int nt = 0; nt < 9; nt++){
    f16x8 bfr0 = *(const f16x8*)&WrkT[(nt * 16 + ln) * 72 + q * 8];
    f16x8 bfr1 = *(const f16x8*)&WrkT[(nt * 16 + ln) * 72 + 32 + q * 8];
#pragma unroll
    for (int mt = 0; mt < 2; mt++){
      acc[mt][nt] = __builtin_amdgcn_mfma_f32_16x16x32_f16(afr[mt][0], bfr0, acc[mt][nt], 0, 0, 0);
      acc[mt][nt] = __builtin_amdgcn_mfma_f32_16x16x32_f16(afr[mt][1], bfr1, acc[mt][nt], 0, 0, 0);
    }
  }
#pragma unroll
  for (int nt = 0; nt < 9; nt++){
    int w = nt * 16 + ln;
    if (w > 128) continue;
#pragma unroll
    for (int mt = 0; mt < 2; mt++){
      int ib = i0 + wave * 32 + mt * 16 + q * 4;
#pragma unroll
      for (int r = 0; r < 4; r++)
        ak[(size_t)(h * 2048 + ib + r) * AKS + w] = acc[mt][nt][r];
    }
  }
}

// ---------------- flash attention, K-split (flash-decoding) ----------------
// blockIdx: x=head, y=qtile(64 rows), z=jhalf (keys [z*1024, z*1024+1024)).
// Writes UNNORMALIZED partial ctx + per-half (m,l). Band logits written in place to akm.
__launch_bounds__(256, 4)
__global__ void flash_kernel(const float* __restrict__ extf,
                             const _Float16* __restrict__ Qf, const _Float16* __restrict__ Kf,
                             const _Float16* __restrict__ Vtf, float* akm,
                             float* __restrict__ ctxpart, float* __restrict__ mws,
                             float* __restrict__ lws){
  __shared__ __attribute__((aligned(16))) _Float16 Ks[128 * 72];   // K tile [j][d]
  __shared__ __attribute__((aligned(16))) _Float16 Vts[64 * 136];  // Vt tile [d][j]
  __shared__ __attribute__((aligned(16))) float exts[128];
  const int h = blockIdx.x, qt = blockIdx.y, jh = blockIdx.z;
  const int t = threadIdx.x, lane = t & 63, wave = t >> 6;
  const int q = lane >> 4, ln = lane & 15;
  const int ibase = qt * 64 + wave * 16;
  const int i = ibase + ln;
  f16x8 qfrag[2];
  {
    const _Float16* qrow = Qf + (size_t)(h * 2048 + i) * 64;
    qfrag[0] = *(const f16x8*)(qrow + q * 8);
    qfrag[1] = *(const f16x8*)(qrow + 32 + q * 8);
  }
  f32x4 accc[4];
#pragma unroll
  for (int dt = 0; dt < 4; dt++) accc[dt] = (f32x4){0.f, 0.f, 0.f, 0.f};
  float m_i = -1.0e30f, l_i = 0.f;
  float* akrow = akm + (size_t)(h * 2048 + i) * AKS;

  for (int jt = 0; jt < 8; jt++){
    const int j0 = jh * 1024 + jt * 128;
#pragma unroll
    for (int c = 0; c < 4; c++){
      int idx = t + 256 * c;
      {
        int row = idx >> 3, col = idx & 7;
        *(f16x8*)&Ks[row * 72 + col * 8] =
            *(const f16x8*)(Kf + (size_t)(h * 2048 + j0 + row) * 64 + col * 8);
      }
      {
        int row = idx >> 4, col = idx & 15;
        *(f16x8*)&Vts[row * 136 + col * 8] =
            *(const f16x8*)(Vtf + (size_t)(h * 64 + row) * 2048 + j0 + col * 8);
      }
    }
    if (t < 128) exts[t] = extf[j0 + t];
    __syncthreads();
    // ---- S^T = K . Q^T ----
    f32x4 s[8];
#pragma unroll
    for (int mt = 0; mt < 8; mt++){
      f16x8 kf0 = *(const f16x8*)&Ks[(mt * 16 + ln) * 72 + q * 8];
      f16x8 kf1 = *(const f16x8*)&Ks[(mt * 16 + ln) * 72 + 32 + q * 8];
      f32x4 zz = (f32x4){0.f, 0.f, 0.f, 0.f};
      zz = __builtin_amdgcn_mfma_f32_16x16x32_f16(kf0, qfrag[0], zz, 0, 0, 0);
      zz = __builtin_amdgcn_mfma_f32_16x16x32_f16(kf1, qfrag[1], zz, 0, 0, 0);
      s[mt] = zz;
    }
    // ---- banded key bias + scale + mask; write back final band logits ----
    const bool band = (j0 <= ibase + 79) && (j0 + 127 >= ibase - 64);
#pragma unroll
    for (int mt = 0; mt < 8; mt++){
      f32x4 ev = *(const f32x4*)&exts[mt * 16 + q * 4];
#pragma unroll
      for (int r = 0; r < 4; r++){
        float x = s[mt][r];
        int w = j0 + mt * 16 + q * 4 + r - i + 64;
        if (band && (unsigned)w <= 128u){
          x = (x + akrow[w]) * 0.125f + ev[r];
          akrow[w] = x;
        } else {
          x = x * 0.125f + ev[r];
        }
        s[mt][r] = x;
      }
    }
    // ---- online softmax ----
    float tmax = -1.0e30f;
#pragma unroll
    for (int mt = 0; mt < 8; mt++)
#pragma unroll
      for (int r = 0; r < 4; r++) tmax = fmaxf(tmax, s[mt][r]);
    tmax = fmaxf(tmax, __shfl_xor(tmax, 16, 64));
    tmax = fmaxf(tmax, __shfl_xor(tmax, 32, 64));
    float mnew = fmaxf(m_i, tmax);
    float alpha = __expf(m_i - mnew);
    m_i = mnew;
    l_i *= alpha;
#pragma unroll
    for (int dt = 0; dt < 4; dt++)
#pragma unroll
      for (int r = 0; r < 4; r++) accc[dt][r] *= alpha;
    float tsum = 0.f;
    f16x4 pf[8];
#pragma unroll
    for (int mt = 0; mt < 8; mt++)
#pragma unroll
      for (int r = 0; r < 4; r++){
        float p = __expf(s[mt][r] - mnew);
        tsum += p;
        pf[mt][r] = (_Float16)p;
      }
    tsum += __shfl_xor(tsum, 16, 64);
    tsum += __shfl_xor(tsum, 32, 64);
    l_i += tsum;
    // ---- PV ----
#pragma unroll
    for (int dt = 0; dt < 4; dt++){
#pragma unroll
      for (int ks = 0; ks < 8; ks++){
        f16x4 vf = *(const f16x4*)&Vts[(dt * 16 + ln) * 136 + ks * 16 + q * 4];
        accc[dt] = __builtin_amdgcn_mfma_f32_16x16x16f16(vf, pf[ks], accc[dt], 0, 0, 0);
      }
    }
    __syncthreads();
  }
  // ---- epilogue: UNNORMALIZED partial ----
  float* cdst = ctxpart + (size_t)jh * NSEQ * HIDDIM;
#pragma unroll
  for (int dt = 0; dt < 4; dt++)
    *(f32x4*)(cdst + (size_t)i * 1024 + h * 64 + dt * 16 + q * 4) = accc[dt];
  if (q == 0){
    mws[jh * NH * NSEQ + h * 2048 + i] = m_i;
    lws[jh * NH * NSEQ + h * 2048 + i] = l_i;
  }
}

// ---------------- finish: merge partials + band correction via MFMA ----------------
// blockIdx: x=qtile(64 rows), y=head. out[i][h*64+d] =
//   (a0*ctx0 + a1*ctx1)/L + sum_w p[i][w]*Wrv[w][d],  p from stored band logits.
__launch_bounds__(256, 2)
__global__ void finish_kernel(const float* __restrict__ sband, const float* __restrict__ mws,
                              const float* __restrict__ lws, const float* __restrict__ wrvf,
                              const float* __restrict__ ctxpart, float* __restrict__ out){
  __shared__ __attribute__((aligned(16))) _Float16 WrvT[64 * 144];  // [d][w], zero-pad w>=129
  __shared__ __attribute__((aligned(16))) _Float16 pT[144 * 72];    // [w][i_local]
  __shared__ __attribute__((aligned(16))) float sM[64], sIL[64], sC0[64], sC1[64];
  const int qt = blockIdx.x, h = blockIdx.y;
  const int i0 = qt * 64;
  const int t = threadIdx.x, lane = t & 63, wave = t >> 6;
  const int q = lane >> 4, ln = lane & 15;
  // stage WrvT (transposed, f16)
  for (int c = 0; c < 36; c++){
    int idx = c * 256 + t;
    int w = idx >> 6, d = idx & 63;
    WrvT[d * 144 + w] = (w < NW) ? (_Float16)wrvf[w * 64 + d] : (_Float16)0.f;
  }
  // per-row merge scalars
  if (t < 64){
    int i = i0 + t;
    float m0 = mws[h * 2048 + i],            m1 = mws[NH * NSEQ + h * 2048 + i];
    float l0 = lws[h * 2048 + i],            l1 = lws[NH * NSEQ + h * 2048 + i];
    float M = fmaxf(m0, m1);
    float a0 = __expf(m0 - M), a1 = __expf(m1 - M);
    float L = a0 * l0 + a1 * l1;
    float iL = 1.f / L;
    sM[t] = M; sIL[t] = iL; sC0[t] = a0 * iL; sC1[t] = a1 * iL;
  }
  __syncthreads();
  // band probs -> pT[w][i_local] (f16)
  for (int ii = 0; ii < 16; ii++){
    int il = wave * 16 + ii;
    float Mv = sM[il], ILv = sIL[il];
    const float* srow = sband + (size_t)(h * 2048 + i0 + il) * AKS;
#pragma unroll
    for (int c = 0; c < 3; c++){
      int w = lane + 64 * c;
      if (w < 144){
        float p = (w < NW) ? __expf(srow[w] - Mv) * ILv : 0.f;
        pT[w * 72 + il] = (_Float16)p;
      }
    }
  }
  __syncthreads();
  // corr^T[d][i] = WrvT . pT via 16x16x16 f16 MFMA (same operand trick as flash PV)
  f32x4 acc[4];
#pragma unroll
  for (int mt = 0; mt < 4; mt++) acc[mt] = (f32x4){0.f, 0.f, 0.f, 0.f};
#pragma unroll
  for (int ks = 0; ks < 9; ks++){
    f16x4 bfr;
#pragma unroll
    for (int j = 0; j < 4; j++) bfr[j] = pT[(ks * 16 + q * 4 + j) * 72 + wave * 16 + ln];
#pragma unroll
    for (int mt = 0; mt < 4; mt++){
      f16x4 afr = *(const f16x4*)&WrvT[(mt * 16 + ln) * 144 + ks * 16 + q * 4];
      acc[mt] = __builtin_amdgcn_mfma_f32_16x16x16f16(afr, bfr, acc[mt], 0, 0, 0);
    }
  }
  // merge partials + store
  const int i = i0 + wave * 16 + ln;
  const float c0 = sC0[wave * 16 + ln], c1 = sC1[wave * 16 + ln];
  const float* p0 = ctxpart;
  const float* p1 = ctxpart + (size_t)NSEQ * HIDDIM;
#pragma unroll
  for (int mt = 0; mt < 4; mt++){
    size_t off = (size_t)i * 1024 + h * 64 + mt * 16 + q * 4;
    f32x4 A0 = *(const f32x4*)(p0 + off);
    f32x4 A1 = *(const f32x4*)(p1 + off);
    f32x4 o4;
#pragma unroll
    for (int r = 0; r < 4; r++) o4[r] = c0 * A0[r] + c1 * A1[r] + acc[mt][r];
    *(f32x4*)(out + off) = o4;
  }
}

// ---------------- launcher ----------------
extern "C" void kernel_launch(void* const* d_in, const int* in_sizes, int n_in,
                              void* d_out, int out_size, void* d_ws, size_t ws_size,
                              hipStream_t stream){
  const void* hs   = d_in[0];
  const void* mask = d_in[1];
  const void* Wq   = d_in[2];
  const void* bq   = d_in[3];
  const void* Wk   = d_in[4];
  const void* bk   = d_in[5];
  const void* Wv   = d_in[6];
  const void* bv   = d_in[7];
  const void* Wrk  = d_in[8];
  const void* Wrv  = d_in[9];
  float* out = (float*)d_out;

  char* ws = (char*)d_ws;
  _Float16* Qf    = (_Float16*)(ws + OFF_Q);
  _Float16* Kf    = (_Float16*)(ws + OFF_K);
  _Float16* Vtf   = (_Float16*)(ws + OFF_VT);
  _Float16* Wt    = (_Float16*)(ws + OFF_WT);
  float*    akp   = (float*)   (ws + OFF_AK);
  float*    mp    = (float*)   (ws + OFF_M);
  float*    lp    = (float*)   (ws + OFF_L);
  float*    ctxp  = (float*)   (ws + OFF_CTXP);
  _Float16* hsf   = (_Float16*)(ws + OFF_HSF);
  float*    biasf = (float*)   (ws + OFF_BIAS);
  float*    wrkf  = (float*)   (ws + OFF_WRK);
  float*    wrvf  = (float*)   (ws + OFF_WRV);
  float*    extf  = (float*)   (ws + OFF_EXT);
  int*      flagp = (int*)     (ws + OFF_FLAG);

  detect_kernel   <<<dim3(1),          1,   0, stream>>>((const unsigned*)mask, flagp);
  cvt_hs_kernel   <<<dim3(1024),       256, 0, stream>>>(hs, flagp, hsf);
  cvt_small_kernel<<<dim3(85),         256, 0, stream>>>(bq, bk, bv, Wrk, Wrv, mask, flagp,
                                                         biasf, wrkf, wrvf, extf);
  wtrans_kernel   <<<dim3(16, 16, 3),  256, 0, stream>>>(Wq, Wk, Wv, flagp, Wt);
  qkv_kernel      <<<dim3(8, 16, 3),   256, 0, stream>>>(hsf, Wt, biasf, Qf, Kf, Vtf);
  ak_kernel       <<<dim3(16, 16),     256, 0, stream>>>(Qf, wrkf, akp);
  flash_kernel    <<<dim3(16, 32, 2),  256, 0, stream>>>(extf, Qf, Kf, Vtf, akp, ctxp, mp, lp);
  finish_kernel   <<<dim3(32, 16),     256, 0, stream>>>(akp, mp, lp, wrvf, ctxp, out);
}